// Round 4
// baseline (525.181 us; speedup 1.0000x reference)
//
#include <hip/hip_runtime.h>
#include <type_traits>

// PerceiverAttentionCA on MI355X (gfx950).  Round 8:
//  - flash_attn v6: T15-style pipeline.  Per tile: {bar1 | stageK(t+1) |
//    QK^T(t)+PV(t-1) fused 68-MFMA setprio cluster | bar2 | stageV(t+1) |
//    softmax(t)}.  Softmax no longer sits between the wave's two MFMA
//    clusters; PV(t-1) accumulates before softmax(t)'s (defer-max-rare)
//    rescale, preserving O_t = O_{t-1}*a_t + P_t V_t exactly.
//    Buffer ledger: K(t-1) dead at bar1 -> stageK early (full-tile flight);
//    V(t-1) read by PV(t-1) in tile t -> stageV after bar2 (softmax flight).
//  - kv GEMM epilogue writes V^T directly (pure-V blocks n0>=2048, packed
//    4xu16 stores); transpose_v kernel deleted.
//  - gemm_bt8 (8-phase 256^2) for kv/out GEMMs, gemm_bt (128^2) for q GEMM.

using u16 = unsigned short;
using u32 = unsigned int;
typedef __attribute__((ext_vector_type(8))) short short8;   // 8 x bf16 bits
typedef __attribute__((ext_vector_type(4))) float floatx4;  // MFMA accumulator
typedef __attribute__((ext_vector_type(4))) unsigned short u16x4;

typedef __attribute__((address_space(1))) const unsigned int gu32;
typedef __attribute__((address_space(3))) unsigned int lu32;

__device__ __forceinline__ void gld16(void* lds, const void* g) {
  __builtin_amdgcn_global_load_lds((gu32*)g, (lu32*)lds, 16, 0, 0);
}

__device__ inline u16 f2bf(float f) {
  u32 u = __float_as_uint(f);
  u32 r = (u + 0x7FFFu + ((u >> 16) & 1u)) >> 16;   // RNE
  return (u16)r;
}

// ---------------------------------------------------------------------------
// LayerNorm + cast to bf16.  One block (256 thr) per row.  L in {2048, 3072}.
// ---------------------------------------------------------------------------
template <int L>
__global__ __launch_bounds__(256) void ln_cast(const float* __restrict__ in,
                                               const float* __restrict__ gw,
                                               const float* __restrict__ bw,
                                               u16* __restrict__ out) {
  constexpr int C4 = L / 1024;
  const int row = blockIdx.x;
  const int t = threadIdx.x;
  const float* rp = in + (size_t)row * L;
  float4 v[C4];
  float s = 0.f, ss = 0.f;
#pragma unroll
  for (int c = 0; c < C4; ++c) {
    v[c] = *(const float4*)(rp + (c * 256 + t) * 4);
    s += v[c].x + v[c].y + v[c].z + v[c].w;
    ss += v[c].x * v[c].x + v[c].y * v[c].y + v[c].z * v[c].z + v[c].w * v[c].w;
  }
#pragma unroll
  for (int off = 32; off > 0; off >>= 1) {
    s += __shfl_down(s, off);
    ss += __shfl_down(ss, off);
  }
  __shared__ float red[8];
  const int wave = t >> 6, lane = t & 63;
  if (lane == 0) { red[wave] = s; red[4 + wave] = ss; }
  __syncthreads();
  const float tot = red[0] + red[1] + red[2] + red[3];
  const float tss = red[4] + red[5] + red[6] + red[7];
  const float mu = tot * (1.f / L);
  const float rstd = rsqrtf(tss * (1.f / L) - mu * mu + 1e-5f);
  u16* op = out + (size_t)row * L;
#pragma unroll
  for (int c = 0; c < C4; ++c) {
    const int base = (c * 256 + t) * 4;
    float4 gv = *(const float4*)(gw + base);
    float4 bv = *(const float4*)(bw + base);
    u32 p0 = (u32)f2bf((v[c].x - mu) * rstd * gv.x + bv.x) |
             ((u32)f2bf((v[c].y - mu) * rstd * gv.y + bv.y) << 16);
    u32 p1 = (u32)f2bf((v[c].z - mu) * rstd * gv.z + bv.z) |
             ((u32)f2bf((v[c].w - mu) * rstd * gv.w + bv.w) << 16);
    uint2 pk; pk.x = p0; pk.y = p1;
    *(uint2*)(op + base) = pk;
  }
}

// ---------------------------------------------------------------------------
// Transpose + cast: fp32 in (R x C) -> bf16 out (C x R).  Block (32,8).
// ---------------------------------------------------------------------------
__global__ __launch_bounds__(256) void transpose_cast(const float* __restrict__ in,
                                                      u16* __restrict__ out,
                                                      int R, int C) {
  __shared__ u16 tile[32][33];
  const int c0 = blockIdx.x * 32, r0 = blockIdx.y * 32;
  const int x = threadIdx.x, y = threadIdx.y;
#pragma unroll
  for (int j = 0; j < 4; ++j)
    tile[y + 8 * j][x] = f2bf(in[(size_t)(r0 + y + 8 * j) * C + c0 + x]);
  __syncthreads();
#pragma unroll
  for (int j = 0; j < 4; ++j)
    out[(size_t)(c0 + y + 8 * j) * R + r0 + x] = tile[x][y + 8 * j];
}

// ---------------------------------------------------------------------------
// GEMM  C(MxN) = A(MxK) * Bt(NxK)^T.  128^2 tile, BK=64 (q GEMM only).
// ---------------------------------------------------------------------------
template <typename OutT>
__global__ __launch_bounds__(256) void gemm_bt(const u16* __restrict__ A,
                                               const u16* __restrict__ Bt,
                                               OutT* __restrict__ C,
                                               int M, int N, int K) {
  __shared__ u16 As[128 * 64];
  __shared__ u16 Bs[128 * 64];
  const int tid = threadIdx.x;
  const int wave = tid >> 6, lane = tid & 63, l16 = lane & 15, quad = lane >> 4;
  const int wm = (wave >> 1) * 64, wn = (wave & 1) * 64;
  const long m0 = (long)blockIdx.y * 128, n0 = (long)blockIdx.x * 128;
  const int srow = tid >> 3;                          // 0..31
  const int gc = ((tid & 7) ^ ((tid >> 3) & 7)) * 8;  // u16 offset
  const u16* Ag0 = A + (m0 + srow) * (long)K + gc;
  const u16* Bg0 = Bt + (n0 + srow) * (long)K + gc;
  const long rowoff = 32L * K;

  const floatx4 fz = {0.f, 0.f, 0.f, 0.f};
  floatx4 acc[4][4];
#pragma unroll
  for (int i = 0; i < 4; ++i)
#pragma unroll
    for (int j = 0; j < 4; ++j) acc[i][j] = fz;

  for (int k0 = 0; k0 < K; k0 += 64) {
    __syncthreads();
#pragma unroll
    for (int c = 0; c < 4; ++c) {
      gld16(&As[(c * 256 + tid) * 8], Ag0 + c * rowoff + k0);
      gld16(&Bs[(c * 256 + tid) * 8], Bg0 + c * rowoff + k0);
    }
    __syncthreads();
#pragma unroll
    for (int kd = 0; kd < 2; ++kd) {
      const int sw = ((4 * kd + quad) ^ (l16 & 7)) * 8;
      short8 a[4], b[4];
#pragma unroll
      for (int i = 0; i < 4; ++i) a[i] = *(const short8*)&As[(wm + i * 16 + l16) * 64 + sw];
#pragma unroll
      for (int j = 0; j < 4; ++j) b[j] = *(const short8*)&Bs[(wn + j * 16 + l16) * 64 + sw];
#pragma unroll
      for (int i = 0; i < 4; ++i)
#pragma unroll
        for (int j = 0; j < 4; ++j)
          acc[i][j] = __builtin_amdgcn_mfma_f32_16x16x32_bf16(a[i], b[j], acc[i][j], 0, 0, 0);
    }
  }

#pragma unroll
  for (int i = 0; i < 4; ++i)
#pragma unroll
    for (int r = 0; r < 4; ++r) {
      const long row = m0 + wm + i * 16 + quad * 4 + r;
#pragma unroll
      for (int j = 0; j < 4; ++j) {
        const long col = n0 + wn + j * 16 + l16;
        if constexpr (std::is_same<OutT, float>::value)
          C[row * N + col] = acc[i][j][r];
        else
          C[row * N + col] = f2bf(acc[i][j][r]);
      }
    }
}

// ---------------------------------------------------------------------------
// 8-phase 256x256 GEMM  C(MxN) = A(MxK) * Bt(NxK)^T.   512 thr, 8 waves.
// See round-7 comments for the vmcnt ledger.  NEW: optional V^T epilogue --
// blocks with n0 >= vcol0 write acc transposed into vT (b,h,128,2048) as
// packed 4xu16 stores and skip the C store (kv GEMM fuses transpose_v).
// ---------------------------------------------------------------------------
#define GBAR()                                         \
  do {                                                 \
    asm volatile("" ::: "memory");                     \
    __builtin_amdgcn_s_barrier();                      \
    asm volatile("" ::: "memory");                     \
  } while (0)
#define VMW(N) asm volatile("s_waitcnt vmcnt(" #N ")" ::: "memory")

#define G8_LDA(MH)                                                             \
  {                                                                            \
    const u16* Ab_ = &As[buf][(MH) * 8192 + (wr * 32 + l16) * 64];             \
    _Pragma("unroll") for (int mi = 0; mi < 2; ++mi)                           \
    _Pragma("unroll") for (int ks = 0; ks < 2; ++ks)                           \
      af[mi][ks] = *(const short8*)&Ab_[mi * 1024 + ((4 * ks + quad) ^ swz) * 8]; \
  }
#define G8_LDB(DST, NH)                                                        \
  {                                                                            \
    const u16* Bb_ = &Bs[buf][(NH) * 8192 + (wc * 64 + l16) * 64];             \
    _Pragma("unroll") for (int ni = 0; ni < 4; ++ni)                           \
    _Pragma("unroll") for (int ks = 0; ks < 2; ++ks)                           \
      DST[ni][ks] = *(const short8*)&Bb_[ni * 1024 + ((4 * ks + quad) ^ swz) * 8]; \
  }
#define G8_MFMA(MH, BFX, NH)                                                   \
  __builtin_amdgcn_s_setprio(1);                                               \
  _Pragma("unroll") for (int ks = 0; ks < 2; ++ks)                             \
  _Pragma("unroll") for (int mi = 0; mi < 2; ++mi)                             \
  _Pragma("unroll") for (int ni = 0; ni < 4; ++ni)                             \
    acc[MH][mi][NH][ni] = __builtin_amdgcn_mfma_f32_16x16x32_bf16(             \
        af[mi][ks], BFX[ni][ks], acc[MH][mi][NH][ni], 0, 0, 0);                \
  __builtin_amdgcn_s_setprio(0);

template <typename OutT>
__global__ __launch_bounds__(512, 2) void gemm_bt8(const u16* __restrict__ A,
                                                   const u16* __restrict__ Bt,
                                                   OutT* __restrict__ C,
                                                   int M, int N, int K,
                                                   u16* __restrict__ vT,
                                                   int vcol0) {
  __shared__ u16 As[2][16384];   // [buf][half][128][64]
  __shared__ u16 Bs[2][16384];
  (void)M;
  const int tid = threadIdx.x;
  const int wave = tid >> 6, lane = tid & 63, l16 = lane & 15, quad = lane >> 4;
  const int wr = wave >> 1;      // 0..3: 32-row strip within the 128-row half
  const int wc = wave & 1;       // 0..1: 64-col strip within the 128-col half
  // XCD-aware bijective swizzle (nwg % 8 == 0 for all our grids)
  const int nwg = gridDim.x * gridDim.y;
  const int bid0 = blockIdx.y * gridDim.x + blockIdx.x;
  const int bid = (bid0 & 7) * (nwg >> 3) + (bid0 >> 3);
  const int bx = bid % gridDim.x, by = bid / gridDim.x;
  const long m0 = (long)by * 256, n0 = (long)bx * 256;

  const int srow = tid >> 3;                       // 0..63
  const int gc = ((tid & 7) ^ (srow & 7)) * 8;     // u16 offset

  auto stageA = [&](int bufn, int h, int k0) {
#pragma unroll
    for (int c = 0; c < 2; ++c)
      gld16(&As[bufn][h * 8192 + (c * 512 + tid) * 8],
            A + (size_t)(m0 + h * 128 + c * 64 + srow) * K + k0 + gc);
  };
  auto stageB = [&](int bufn, int h, int k0) {
#pragma unroll
    for (int c = 0; c < 2; ++c)
      gld16(&Bs[bufn][h * 8192 + (c * 512 + tid) * 8],
            Bt + (size_t)(n0 + h * 128 + c * 64 + srow) * K + k0 + gc);
  };

  const floatx4 fz = {0.f, 0.f, 0.f, 0.f};
  floatx4 acc[2][2][2][4];
#pragma unroll
  for (int a = 0; a < 2; ++a)
#pragma unroll
    for (int b = 0; b < 2; ++b)
#pragma unroll
      for (int c = 0; c < 2; ++c)
#pragma unroll
        for (int d = 0; d < 4; ++d) acc[a][b][c][d] = fz;

  short8 af[2][2], bf0[4][2], bf1[4][2];
  const int swz = l16 & 7;

  // prologue: stage tile 0 in need order; wait A0,B0 (leave B1,A1 in flight)
  stageA(0, 0, 0);
  stageB(0, 0, 0);
  stageB(0, 1, 0);
  stageA(0, 1, 0);
  VMW(4);
  GBAR();

  const int NT = K >> 6;
  for (int t = 0; t < NT; ++t) {
    const int buf = t & 1;
    const int kn = (t + 1) << 6;
    const bool pre = (t + 1 < NT);

    // ---- phase 0: quadrant (0,0) ----
    G8_LDA(0);
    G8_LDB(bf0, 0);
    if (pre) stageA(buf ^ 1, 0, kn);
    GBAR();
    G8_MFMA(0, bf0, 0);
    if (pre) { VMW(4); } else { VMW(2); }   // B1(t) landed
    GBAR();

    // ---- phase 1: quadrant (0,1) ----
    G8_LDB(bf1, 1);
    if (pre) stageB(buf ^ 1, 0, kn);
    GBAR();
    G8_MFMA(0, bf1, 1);
    if (pre) { VMW(4); } else { VMW(0); }   // A1(t) landed
    GBAR();

    // ---- phase 2: quadrant (1,0) ----
    G8_LDA(1);
    if (pre) stageB(buf ^ 1, 1, kn);
    GBAR();
    G8_MFMA(1, bf0, 0);
    GBAR();

    // ---- phase 3: quadrant (1,1) ----
    if (pre) stageA(buf ^ 1, 1, kn);
    GBAR();
    G8_MFMA(1, bf1, 1);
    if (pre) { VMW(4); }                    // A0,B0(t+1) landed
    GBAR();
  }

  // epilogue
  bool vpath = false;
  if constexpr (std::is_same<OutT, u16>::value) vpath = (n0 >= vcol0);
  if (vpath) {
    // V^T path: vT[(b*16+h)*128 + d][n] = C[row=b*2048+n][col=vcol0+h*128+d]
#pragma unroll
    for (int mh = 0; mh < 2; ++mh)
#pragma unroll
      for (int mi = 0; mi < 2; ++mi) {
        const long row_base = m0 + mh * 128 + wr * 32 + mi * 16 + quad * 4;
        const long bb = row_base >> 11, nn = row_base & 2047;
#pragma unroll
        for (int nh = 0; nh < 2; ++nh)
#pragma unroll
          for (int ni = 0; ni < 4; ++ni) {
            const long col = n0 + nh * 128 + wc * 64 + ni * 16 + l16 - vcol0;
            const long hh = col >> 7, dd = col & 127;
            u16x4 pk;
#pragma unroll
            for (int rr = 0; rr < 4; ++rr) pk[rr] = f2bf(acc[mh][mi][nh][ni][rr]);
            *(u16x4*)&vT[(((bb * 16 + hh) * 128 + dd) << 11) + nn] = pk;
          }
      }
  } else {
#pragma unroll
    for (int mh = 0; mh < 2; ++mh)
#pragma unroll
      for (int mi = 0; mi < 2; ++mi)
#pragma unroll
        for (int rr = 0; rr < 4; ++rr) {
          const long row = m0 + mh * 128 + wr * 32 + mi * 16 + quad * 4 + rr;
#pragma unroll
          for (int nh = 0; nh < 2; ++nh)
#pragma unroll
            for (int ni = 0; ni < 4; ++ni) {
              const long col = n0 + nh * 128 + wc * 64 + ni * 16 + l16;
              if constexpr (std::is_same<OutT, float>::value)
                C[row * N + col] = acc[mh][mi][nh][ni][rr];
              else
                C[row * N + col] = f2bf(acc[mh][mi][nh][ni][rr]);
            }
        }
  }
}

#undef G8_LDA
#undef G8_LDB
#undef G8_MFMA

// ---------------------------------------------------------------------------
// Flash attention v6 (T15 pipeline).  Grid 512 blocks (XCD head-clustered),
// 4 waves, 32 q-rows/wave, kv-tile 64, double-buffered K/V (80 KB, 2 blk/CU).
// Tile t: bar1 | stageK(t+1) | QK^T(t)+PV(t-1) | bar2 | stageV(t+1) | softmax(t).
// Buffer ledger: bar1 drains stage(t) DMA; K(t-1) dead at bar1 -> stageK early;
// V(t-1) read by PV(t-1) -> bar2 before stageV overwrites it.  Rescale order
// preserved: PV(t-1) accumulates before softmax(t)'s alpha multiply.
// ---------------------------------------------------------------------------
__global__ __launch_bounds__(256, 2) void flash_attn(const u16* __restrict__ Q,
                                                     const u16* __restrict__ KV,
                                                     const u16* __restrict__ VT,
                                                     u16* __restrict__ O) {
  __shared__ u16 Ks[2][64 * 128];    // [kv][16 chunks], chunk^= (kv&15)
  __shared__ u16 Vs[2][128 * 64];    // [d][8 chunks],   chunk^= (d&7)
  __shared__ u16 Ps[4][32 * 64];     // per-wave [q][8 chunks], chunk^=((q&7)^(q>>3))
  const int tid = threadIdx.x;
  const int wave = tid >> 6, lane = tid & 63, l16 = lane & 15, quad = lane >> 4;
  const int d = blockIdx.x;
  const int bh = (d & 7) * 4 + ((d >> 3) & 3);
  const int qt = d >> 5;
  const int b = bh >> 4, h = bh & 15;
  const u16* Qb = Q + (size_t)b * 2048 * 2048 + h * 128;
  const u16* Kb = KV + (size_t)b * 2048 * 4096 + h * 128;
  const u16* Vb = VT + (size_t)bh * 128 * 2048;
  u16* Ob = O + (size_t)b * 2048 * 2048 + h * 128;
  const int q0 = qt * 128 + wave * 32;

  short8 qf[2][4];
#pragma unroll
  for (int t = 0; t < 2; ++t)
#pragma unroll
    for (int kd = 0; kd < 4; ++kd)
      qf[t][kd] = *(const short8*)&Qb[(size_t)(q0 + t * 16 + l16) * 2048 + kd * 32 + quad * 8];

  short8 onesf;
  {
    union { short8 s; u32 w[4]; } uo;
    const u32 o = (l16 == 0) ? 0x3F803F80u : 0u;
#pragma unroll
    for (int i = 0; i < 4; ++i) uo.w[i] = o;
    onesf = uo.s;
  }

  const floatx4 fz = {0.f, 0.f, 0.f, 0.f};
  floatx4 oacc[2][9];
  float m[2][4];
#pragma unroll
  for (int t = 0; t < 2; ++t) {
#pragma unroll
    for (int jd = 0; jd < 9; ++jd) oacc[t][jd] = fz;
#pragma unroll
    for (int r = 0; r < 4; ++r) m[t][r] = -1e30f;
  }

  u16* Psw = Ps[wave];
  const float sc2 = 0.12751775f;   // (1/sqrt(128)) * log2(e)
  const float THR2 = 11.5416f;     // defer-max threshold 8 (ln) in log2 space
  const int pmask0 = (l16 & 7) ^ (l16 >> 3);        // P read swizzle, t=0
  const int pmask1 = (l16 & 7) ^ (2 + (l16 >> 3));  // P read swizzle, t=1

  auto stageK = [&](int buf, int kv0) {
#pragma unroll
    for (int c = 0; c < 4; ++c) {
      const int li = c * 256 + tid;
      const int krow = li >> 4, kdb = (li & 15) ^ (krow & 15);
      gld16(&Ks[buf][li * 8], Kb + (size_t)(kv0 + krow) * 4096 + kdb * 8);
    }
  };
  auto stageV = [&](int buf, int kv0) {
#pragma unroll
    for (int c = 0; c < 4; ++c) {
      const int li = c * 256 + tid;
      const int vrow = li >> 3, vdb = (li & 7) ^ (vrow & 7);
      gld16(&Vs[buf][li * 8], Vb + (size_t)vrow * 2048 + kv0 + vdb * 8);
    }
  };

  stageK(0, 0);
  stageV(0, 0);
  int cur = 0;

  for (int kt = 0; kt < 32; ++kt) {
    __syncthreads();                 // bar1: stage(kt) DMA drained
    if (kt < 31) stageK(cur ^ 1, (kt + 1) * 64);   // K(kt-1) dead: safe now
    const u16* Kc = Ks[cur];
    const u16* Vp = Vs[cur ^ 1];     // V of tile kt-1 (valid for kt>0)

    // fused MFMA cluster: S = Q K^T (kt)  then  O += P V (kt-1)
    floatx4 sacc[2][4];
#pragma unroll
    for (int t = 0; t < 2; ++t)
#pragma unroll
      for (int jn = 0; jn < 4; ++jn) sacc[t][jn] = fz;
    __builtin_amdgcn_s_setprio(1);
#pragma unroll
    for (int jn = 0; jn < 4; ++jn)
#pragma unroll
      for (int kd = 0; kd < 4; ++kd) {
        short8 kb = *(const short8*)&Kc[(jn * 16 + l16) * 128 + ((4 * kd + quad) ^ l16) * 8];
        sacc[0][jn] = __builtin_amdgcn_mfma_f32_16x16x32_bf16(qf[0][kd], kb, sacc[0][jn], 0, 0, 0);
        sacc[1][jn] = __builtin_amdgcn_mfma_f32_16x16x32_bf16(qf[1][kd], kb, sacc[1][jn], 0, 0, 0);
      }
    if (kt > 0) {
#pragma unroll
      for (int kk = 0; kk < 2; ++kk) {
        const int chunk = 4 * kk + quad;
        short8 pf0 = *(const short8*)&Psw[(l16) * 64 + (chunk ^ pmask0) * 8];
        short8 pf1 = *(const short8*)&Psw[(16 + l16) * 64 + (chunk ^ pmask1) * 8];
#pragma unroll
        for (int jd = 0; jd < 8; ++jd) {
          short8 vb = *(const short8*)&Vp[(jd * 16 + l16) * 64 + (chunk ^ (l16 & 7)) * 8];
          oacc[0][jd] = __builtin_amdgcn_mfma_f32_16x16x32_bf16(pf0, vb, oacc[0][jd], 0, 0, 0);
          oacc[1][jd] = __builtin_amdgcn_mfma_f32_16x16x32_bf16(pf1, vb, oacc[1][jd], 0, 0, 0);
        }
        oacc[0][8] = __builtin_amdgcn_mfma_f32_16x16x32_bf16(pf0, onesf, oacc[0][8], 0, 0, 0);
        oacc[1][8] = __builtin_amdgcn_mfma_f32_16x16x32_bf16(pf1, onesf, oacc[1][8], 0, 0, 0);
      }
    }
    __builtin_amdgcn_s_setprio(0);

    __syncthreads();                 // bar2: all waves done reading Vs[cur^1]
    if (kt < 31) stageV(cur ^ 1, (kt + 1) * 64);   // overlaps softmax below

    // softmax(kt): sacc -> P(kt) in Psw; defer-max rescale of oacc (rare)
#pragma unroll
    for (int t = 0; t < 2; ++t) {
#pragma unroll
      for (int r = 0; r < 4; ++r) {
        float mx = fmaxf(fmaxf(sacc[t][0][r], sacc[t][1][r]),
                         fmaxf(sacc[t][2][r], sacc[t][3][r]));
#pragma unroll
        for (int off = 8; off > 0; off >>= 1) mx = fmaxf(mx, __shfl_xor(mx, off, 16));
        const float mxs = sc2 * mx;
        if (!__all(mxs - m[t][r] <= THR2)) {
          const float mnew = fmaxf(m[t][r], mxs);
          const float alpha = __builtin_amdgcn_exp2f(m[t][r] - mnew);
          m[t][r] = mnew;
#pragma unroll
          for (int jd = 0; jd < 9; ++jd) oacc[t][jd][r] *= alpha;
        }
        const float mrow = m[t][r];
        const int q = t * 16 + quad * 4 + r;               // 0..31
        const int mask = (q & 7) ^ (q >> 3);
        u16* prow = &Psw[q * 64 + (l16 & 7)];
#pragma unroll
        for (int jn = 0; jn < 4; ++jn) {
          const float p = __builtin_amdgcn_exp2f(fmaf(sc2, sacc[t][jn][r], -mrow));
          const int slot = (2 * jn + (l16 >> 3)) ^ mask;
          prow[slot * 8] = f2bf(p);
        }
      }
    }
    cur ^= 1;
  }

  // final PV(31): V(31) is in Vs[cur^1] (cur==0 after 32 flips), P(31) in Psw
  {
    const u16* Vp = Vs[cur ^ 1];
    __builtin_amdgcn_s_setprio(1);
#pragma unroll
    for (int kk = 0; kk < 2; ++kk) {
      const int chunk = 4 * kk + quad;
      short8 pf0 = *(const short8*)&Psw[(l16) * 64 + (chunk ^ pmask0) * 8];
      short8 pf1 = *(const short8*)&Psw[(16 + l16) * 64 + (chunk ^ pmask1) * 8];
#pragma unroll
      for (int jd = 0; jd < 8; ++jd) {
        short8 vb = *(const short8*)&Vp[(jd * 16 + l16) * 64 + (chunk ^ (l16 & 7)) * 8];
        oacc[0][jd] = __builtin_amdgcn_mfma_f32_16x16x32_bf16(pf0, vb, oacc[0][jd], 0, 0, 0);
        oacc[1][jd] = __builtin_amdgcn_mfma_f32_16x16x32_bf16(pf1, vb, oacc[1][jd], 0, 0, 0);
      }
      oacc[0][8] = __builtin_amdgcn_mfma_f32_16x16x32_bf16(pf0, onesf, oacc[0][8], 0, 0, 0);
      oacc[1][8] = __builtin_amdgcn_mfma_f32_16x16x32_bf16(pf1, onesf, oacc[1][8], 0, 0, 0);
    }
    __builtin_amdgcn_s_setprio(0);
  }

  // epilogue: l from ones-column; divide, store
#pragma unroll
  for (int t = 0; t < 2; ++t)
#pragma unroll
    for (int r = 0; r < 4; ++r) {
      const float l = __shfl(oacc[t][8][r], lane & 48);
      const float inv = 1.f / l;
      const size_t row = q0 + t * 16 + quad * 4 + r;
#pragma unroll
      for (int jd = 0; jd < 8; ++jd)
        Ob[row * 2048 + jd * 16 + l16] = f2bf(oacc[t][jd][r] * inv);
    }
}

// ---------------------------------------------------------------------------
extern "C" void kernel_launch(void* const* d_in, const int* in_sizes, int n_in,
                              void* d_out, int out_size, void* d_ws, size_t ws_size,
                              hipStream_t stream) {
  const float* x       = (const float*)d_in[0];
  const float* latents = (const float*)d_in[1];
  const float* w_q     = (const float*)d_in[2];
  const float* w_kv    = (const float*)d_in[3];
  const float* w_out   = (const float*)d_in[4];
  const float* ln1_g   = (const float*)d_in[5];
  const float* ln1_b   = (const float*)d_in[6];
  const float* ln2_g   = (const float*)d_in[7];
  const float* ln2_b   = (const float*)d_in[8];

  char* ws = (char*)d_ws;
  u16* xn    = (u16*)(ws);              // LN(x)        [dead after kv gemm]
  u16* lnl   = (u16*)(ws + 16777216);   // LN(latents)  [dead after q gemm]
  u16* wqT   = (u16*)(ws + 41943040);
  u16* wkvT  = (u16*)(ws + 54525952);
  u16* woutT = (u16*)(ws + 71303168);
  u16* qb    = (u16*)(ws + 83886080);
  u16* kvb   = (u16*)(ws + 100663296);
  u16* vTb   = lnl;                     // alias (q gemm consumed lnl already)
  u16* attn  = xn;                      // alias

  ln_cast<2048><<<dim3(4096), 256, 0, stream>>>(x, ln1_g, ln1_b, xn);
  ln_cast<3072><<<dim3(4096), 256, 0, stream>>>(latents, ln2_g, ln2_b, lnl);

  transpose_cast<<<dim3(64, 96), dim3(32, 8), 0, stream>>>(w_q, wqT, 3072, 2048);
  transpose_cast<<<dim3(128, 64), dim3(32, 8), 0, stream>>>(w_kv, wkvT, 2048, 4096);
  transpose_cast<<<dim3(96, 64), dim3(32, 8), 0, stream>>>(w_out, woutT, 2048, 3072);

  gemm_bt<u16><<<dim3(16, 32), 256, 0, stream>>>(lnl, wqT, qb, 4096, 2048, 3072);
  // kv GEMM: K half -> kvb, V half -> vTb transposed (fused transpose_v)
  gemm_bt8<u16><<<dim3(16, 16), 512, 0, stream>>>(xn, wkvT, kvb, 4096, 4096, 2048,
                                                  vTb, 2048);

  flash_attn<<<dim3(512), 256, 0, stream>>>(qb, kvb, vTb, attn);

  gemm_bt8<float><<<dim3(12, 16), 512, 0, stream>>>(attn, woutT, (float*)d_out,
                                                    4096, 3072, 2048, nullptr,
                                                    1 << 30);
}

// Round 5
// 506.046 us; speedup vs baseline: 1.0378x; 1.0378x over previous
//
#include <hip/hip_runtime.h>
#include <type_traits>

// PerceiverAttentionCA on MI355X (gfx950).  Round 9:
//  - flash_attn: REVERT to round-7 v5 (124.5 us: setprio + defer-max,
//    single fused tile loop).  Round-8's T15 pipeline (+1 barrier/tile)
//    regressed to 128.7 us.
//  - kv GEMM V^T fusion KEPT but store path FIXED: round-8's scatter
//    u16x4 stores (stride-2048 rows -> 8x write amplification, ~+15 us)
//    replaced by an LDS-staged transpose per 128x128 quadrant: acc ->
//    padded LDS tile [128][136] u16 -> coalesced 256 B row stores.
//    transpose_v kernel stays deleted.
//  - gemm_bt8 (8-phase 256^2) for kv/out GEMMs, gemm_bt (128^2) for q GEMM.

using u16 = unsigned short;
using u32 = unsigned int;
typedef __attribute__((ext_vector_type(8))) short short8;   // 8 x bf16 bits
typedef __attribute__((ext_vector_type(4))) float floatx4;  // MFMA accumulator
typedef __attribute__((ext_vector_type(4))) unsigned short u16x4;

typedef __attribute__((address_space(1))) const unsigned int gu32;
typedef __attribute__((address_space(3))) unsigned int lu32;

__device__ __forceinline__ void gld16(void* lds, const void* g) {
  __builtin_amdgcn_global_load_lds((gu32*)g, (lu32*)lds, 16, 0, 0);
}

__device__ inline u16 f2bf(float f) {
  u32 u = __float_as_uint(f);
  u32 r = (u + 0x7FFFu + ((u >> 16) & 1u)) >> 16;   // RNE
  return (u16)r;
}

// ---------------------------------------------------------------------------
// LayerNorm + cast to bf16.  One block (256 thr) per row.  L in {2048, 3072}.
// ---------------------------------------------------------------------------
template <int L>
__global__ __launch_bounds__(256) void ln_cast(const float* __restrict__ in,
                                               const float* __restrict__ gw,
                                               const float* __restrict__ bw,
                                               u16* __restrict__ out) {
  constexpr int C4 = L / 1024;
  const int row = blockIdx.x;
  const int t = threadIdx.x;
  const float* rp = in + (size_t)row * L;
  float4 v[C4];
  float s = 0.f, ss = 0.f;
#pragma unroll
  for (int c = 0; c < C4; ++c) {
    v[c] = *(const float4*)(rp + (c * 256 + t) * 4);
    s += v[c].x + v[c].y + v[c].z + v[c].w;
    ss += v[c].x * v[c].x + v[c].y * v[c].y + v[c].z * v[c].z + v[c].w * v[c].w;
  }
#pragma unroll
  for (int off = 32; off > 0; off >>= 1) {
    s += __shfl_down(s, off);
    ss += __shfl_down(ss, off);
  }
  __shared__ float red[8];
  const int wave = t >> 6, lane = t & 63;
  if (lane == 0) { red[wave] = s; red[4 + wave] = ss; }
  __syncthreads();
  const float tot = red[0] + red[1] + red[2] + red[3];
  const float tss = red[4] + red[5] + red[6] + red[7];
  const float mu = tot * (1.f / L);
  const float rstd = rsqrtf(tss * (1.f / L) - mu * mu + 1e-5f);
  u16* op = out + (size_t)row * L;
#pragma unroll
  for (int c = 0; c < C4; ++c) {
    const int base = (c * 256 + t) * 4;
    float4 gv = *(const float4*)(gw + base);
    float4 bv = *(const float4*)(bw + base);
    u32 p0 = (u32)f2bf((v[c].x - mu) * rstd * gv.x + bv.x) |
             ((u32)f2bf((v[c].y - mu) * rstd * gv.y + bv.y) << 16);
    u32 p1 = (u32)f2bf((v[c].z - mu) * rstd * gv.z + bv.z) |
             ((u32)f2bf((v[c].w - mu) * rstd * gv.w + bv.w) << 16);
    uint2 pk; pk.x = p0; pk.y = p1;
    *(uint2*)(op + base) = pk;
  }
}

// ---------------------------------------------------------------------------
// Transpose + cast: fp32 in (R x C) -> bf16 out (C x R).  Block (32,8).
// ---------------------------------------------------------------------------
__global__ __launch_bounds__(256) void transpose_cast(const float* __restrict__ in,
                                                      u16* __restrict__ out,
                                                      int R, int C) {
  __shared__ u16 tile[32][33];
  const int c0 = blockIdx.x * 32, r0 = blockIdx.y * 32;
  const int x = threadIdx.x, y = threadIdx.y;
#pragma unroll
  for (int j = 0; j < 4; ++j)
    tile[y + 8 * j][x] = f2bf(in[(size_t)(r0 + y + 8 * j) * C + c0 + x]);
  __syncthreads();
#pragma unroll
  for (int j = 0; j < 4; ++j)
    out[(size_t)(c0 + y + 8 * j) * R + r0 + x] = tile[x][y + 8 * j];
}

// ---------------------------------------------------------------------------
// GEMM  C(MxN) = A(MxK) * Bt(NxK)^T.  128^2 tile, BK=64 (q GEMM only).
// ---------------------------------------------------------------------------
template <typename OutT>
__global__ __launch_bounds__(256) void gemm_bt(const u16* __restrict__ A,
                                               const u16* __restrict__ Bt,
                                               OutT* __restrict__ C,
                                               int M, int N, int K) {
  __shared__ u16 As[128 * 64];
  __shared__ u16 Bs[128 * 64];
  const int tid = threadIdx.x;
  const int wave = tid >> 6, lane = tid & 63, l16 = lane & 15, quad = lane >> 4;
  const int wm = (wave >> 1) * 64, wn = (wave & 1) * 64;
  const long m0 = (long)blockIdx.y * 128, n0 = (long)blockIdx.x * 128;
  const int srow = tid >> 3;                          // 0..31
  const int gc = ((tid & 7) ^ ((tid >> 3) & 7)) * 8;  // u16 offset
  const u16* Ag0 = A + (m0 + srow) * (long)K + gc;
  const u16* Bg0 = Bt + (n0 + srow) * (long)K + gc;
  const long rowoff = 32L * K;

  const floatx4 fz = {0.f, 0.f, 0.f, 0.f};
  floatx4 acc[4][4];
#pragma unroll
  for (int i = 0; i < 4; ++i)
#pragma unroll
    for (int j = 0; j < 4; ++j) acc[i][j] = fz;

  for (int k0 = 0; k0 < K; k0 += 64) {
    __syncthreads();
#pragma unroll
    for (int c = 0; c < 4; ++c) {
      gld16(&As[(c * 256 + tid) * 8], Ag0 + c * rowoff + k0);
      gld16(&Bs[(c * 256 + tid) * 8], Bg0 + c * rowoff + k0);
    }
    __syncthreads();
#pragma unroll
    for (int kd = 0; kd < 2; ++kd) {
      const int sw = ((4 * kd + quad) ^ (l16 & 7)) * 8;
      short8 a[4], b[4];
#pragma unroll
      for (int i = 0; i < 4; ++i) a[i] = *(const short8*)&As[(wm + i * 16 + l16) * 64 + sw];
#pragma unroll
      for (int j = 0; j < 4; ++j) b[j] = *(const short8*)&Bs[(wn + j * 16 + l16) * 64 + sw];
#pragma unroll
      for (int i = 0; i < 4; ++i)
#pragma unroll
        for (int j = 0; j < 4; ++j)
          acc[i][j] = __builtin_amdgcn_mfma_f32_16x16x32_bf16(a[i], b[j], acc[i][j], 0, 0, 0);
    }
  }

#pragma unroll
  for (int i = 0; i < 4; ++i)
#pragma unroll
    for (int r = 0; r < 4; ++r) {
      const long row = m0 + wm + i * 16 + quad * 4 + r;
#pragma unroll
      for (int j = 0; j < 4; ++j) {
        const long col = n0 + wn + j * 16 + l16;
        if constexpr (std::is_same<OutT, float>::value)
          C[row * N + col] = acc[i][j][r];
        else
          C[row * N + col] = f2bf(acc[i][j][r]);
      }
    }
}

// ---------------------------------------------------------------------------
// 8-phase 256x256 GEMM  C(MxN) = A(MxK) * Bt(NxK)^T.   512 thr, 8 waves.
// vmcnt ledger (see round-7): in-flight never below 2 half-tiles; vmcnt(4)
// closes phases 0/1/3.  V^T epilogue: blocks with n0 >= vcol0 (kv GEMM's
// pure-V half) write acc as vT (b,h,128,2048) via an LDS-staged transpose
// (padded [128][136] u16 tile -> fully coalesced 256 B row stores).
// ---------------------------------------------------------------------------
#define GBAR()                                         \
  do {                                                 \
    asm volatile("" ::: "memory");                     \
    __builtin_amdgcn_s_barrier();                      \
    asm volatile("" ::: "memory");                     \
  } while (0)
#define VMW(N) asm volatile("s_waitcnt vmcnt(" #N ")" ::: "memory")

#define G8_LDA(MH)                                                             \
  {                                                                            \
    const u16* Ab_ = &As[buf][(MH) * 8192 + (wr * 32 + l16) * 64];             \
    _Pragma("unroll") for (int mi = 0; mi < 2; ++mi)                           \
    _Pragma("unroll") for (int ks = 0; ks < 2; ++ks)                           \
      af[mi][ks] = *(const short8*)&Ab_[mi * 1024 + ((4 * ks + quad) ^ swz) * 8]; \
  }
#define G8_LDB(DST, NH)                                                        \
  {                                                                            \
    const u16* Bb_ = &Bs[buf][(NH) * 8192 + (wc * 64 + l16) * 64];             \
    _Pragma("unroll") for (int ni = 0; ni < 4; ++ni)                           \
    _Pragma("unroll") for (int ks = 0; ks < 2; ++ks)                           \
      DST[ni][ks] = *(const short8*)&Bb_[ni * 1024 + ((4 * ks + quad) ^ swz) * 8]; \
  }
#define G8_MFMA(MH, BFX, NH)                                                   \
  __builtin_amdgcn_s_setprio(1);                                               \
  _Pragma("unroll") for (int ks = 0; ks < 2; ++ks)                             \
  _Pragma("unroll") for (int mi = 0; mi < 2; ++mi)                             \
  _Pragma("unroll") for (int ni = 0; ni < 4; ++ni)                             \
    acc[MH][mi][NH][ni] = __builtin_amdgcn_mfma_f32_16x16x32_bf16(             \
        af[mi][ks], BFX[ni][ks], acc[MH][mi][NH][ni], 0, 0, 0);                \
  __builtin_amdgcn_s_setprio(0);

template <typename OutT>
__global__ __launch_bounds__(512, 2) void gemm_bt8(const u16* __restrict__ A,
                                                   const u16* __restrict__ Bt,
                                                   OutT* __restrict__ C,
                                                   int M, int N, int K,
                                                   u16* __restrict__ vT,
                                                   int vcol0) {
  __shared__ u16 As[2][16384];   // [buf][half][128][64]
  __shared__ u16 Bs[2][16384];
  (void)M;
  const int tid = threadIdx.x;
  const int wave = tid >> 6, lane = tid & 63, l16 = lane & 15, quad = lane >> 4;
  const int wr = wave >> 1;      // 0..3: 32-row strip within the 128-row half
  const int wc = wave & 1;       // 0..1: 64-col strip within the 128-col half
  // XCD-aware bijective swizzle (nwg % 8 == 0 for all our grids)
  const int nwg = gridDim.x * gridDim.y;
  const int bid0 = blockIdx.y * gridDim.x + blockIdx.x;
  const int bid = (bid0 & 7) * (nwg >> 3) + (bid0 >> 3);
  const int bx = bid % gridDim.x, by = bid / gridDim.x;
  const long m0 = (long)by * 256, n0 = (long)bx * 256;

  const int srow = tid >> 3;                       // 0..63
  const int gc = ((tid & 7) ^ (srow & 7)) * 8;     // u16 offset

  auto stageA = [&](int bufn, int h, int k0) {
#pragma unroll
    for (int c = 0; c < 2; ++c)
      gld16(&As[bufn][h * 8192 + (c * 512 + tid) * 8],
            A + (size_t)(m0 + h * 128 + c * 64 + srow) * K + k0 + gc);
  };
  auto stageB = [&](int bufn, int h, int k0) {
#pragma unroll
    for (int c = 0; c < 2; ++c)
      gld16(&Bs[bufn][h * 8192 + (c * 512 + tid) * 8],
            Bt + (size_t)(n0 + h * 128 + c * 64 + srow) * K + k0 + gc);
  };

  const floatx4 fz = {0.f, 0.f, 0.f, 0.f};
  floatx4 acc[2][2][2][4];
#pragma unroll
  for (int a = 0; a < 2; ++a)
#pragma unroll
    for (int b = 0; b < 2; ++b)
#pragma unroll
      for (int c = 0; c < 2; ++c)
#pragma unroll
        for (int d = 0; d < 4; ++d) acc[a][b][c][d] = fz;

  short8 af[2][2], bf0[4][2], bf1[4][2];
  const int swz = l16 & 7;

  // prologue: stage tile 0 in need order; wait A0,B0 (leave B1,A1 in flight)
  stageA(0, 0, 0);
  stageB(0, 0, 0);
  stageB(0, 1, 0);
  stageA(0, 1, 0);
  VMW(4);
  GBAR();

  const int NT = K >> 6;
  for (int t = 0; t < NT; ++t) {
    const int buf = t & 1;
    const int kn = (t + 1) << 6;
    const bool pre = (t + 1 < NT);

    // ---- phase 0: quadrant (0,0) ----
    G8_LDA(0);
    G8_LDB(bf0, 0);
    if (pre) stageA(buf ^ 1, 0, kn);
    GBAR();
    G8_MFMA(0, bf0, 0);
    if (pre) { VMW(4); } else { VMW(2); }   // B1(t) landed
    GBAR();

    // ---- phase 1: quadrant (0,1) ----
    G8_LDB(bf1, 1);
    if (pre) stageB(buf ^ 1, 0, kn);
    GBAR();
    G8_MFMA(0, bf1, 1);
    if (pre) { VMW(4); } else { VMW(0); }   // A1(t) landed
    GBAR();

    // ---- phase 2: quadrant (1,0) ----
    G8_LDA(1);
    if (pre) stageB(buf ^ 1, 1, kn);
    GBAR();
    G8_MFMA(1, bf0, 0);
    GBAR();

    // ---- phase 3: quadrant (1,1) ----
    if (pre) stageA(buf ^ 1, 1, kn);
    GBAR();
    G8_MFMA(1, bf1, 1);
    if (pre) { VMW(4); }                    // A0,B0(t+1) landed
    GBAR();
  }

  // epilogue
  bool vpath = false;
  if constexpr (std::is_same<OutT, u16>::value) vpath = (n0 >= vcol0);
  if (vpath) {
    // Fused transpose_v, coalesced: per 128x128 quadrant stage acc into a
    // padded LDS tile T[d_local][136] (u16; stride 136 -> 272 B rows, 16 B
    // aligned for b128 reads, n_local*2 8 B aligned for b64 writes), then
    // stream out 256 B-contiguous V^T rows (4 threads cover one d-row).
    u16* tl = (u16*)&As[0][0];          // 128*136*2 = 34816 B scratch
#pragma unroll
    for (int mh = 0; mh < 2; ++mh)
#pragma unroll
      for (int nh = 0; nh < 2; ++nh) {
        const long R0 = m0 + mh * 128;
        const long bb = R0 >> 11, nn0 = R0 & 2047;
        const long hh = (n0 + nh * 128 - vcol0) >> 7;
        __syncthreads();                // prev quadrant's LDS reads complete
        const int dl0 = wc * 64 + l16;
        const int nl0 = wr * 32 + quad * 4;
#pragma unroll
        for (int mi = 0; mi < 2; ++mi)
#pragma unroll
          for (int ni = 0; ni < 4; ++ni) {
            u16x4 pk;
#pragma unroll
            for (int rr = 0; rr < 4; ++rr) pk[rr] = f2bf(acc[mh][mi][nh][ni][rr]);
            *(u16x4*)&tl[(dl0 + ni * 16) * 136 + nl0 + mi * 16] = pk;
          }
        __syncthreads();
        const int d = tid >> 2, sg = (tid & 3) * 32;
        u16* gp = &vT[(((bb * 16 + hh) * 128 + d) << 11) + nn0 + sg];
        const u16* lp = &tl[d * 136 + sg];
#pragma unroll
        for (int j = 0; j < 4; ++j)
          *(short8*)&gp[j * 8] = *(const short8*)&lp[j * 8];
      }
  } else {
#pragma unroll
    for (int mh = 0; mh < 2; ++mh)
#pragma unroll
      for (int mi = 0; mi < 2; ++mi)
#pragma unroll
        for (int rr = 0; rr < 4; ++rr) {
          const long row = m0 + mh * 128 + wr * 32 + mi * 16 + quad * 4 + rr;
#pragma unroll
          for (int nh = 0; nh < 2; ++nh)
#pragma unroll
            for (int ni = 0; ni < 4; ++ni) {
              const long col = n0 + nh * 128 + wc * 64 + ni * 16 + l16;
              if constexpr (std::is_same<OutT, float>::value)
                C[row * N + col] = acc[mh][mi][nh][ni][rr];
              else
                C[row * N + col] = f2bf(acc[mh][mi][nh][ni][rr]);
            }
        }
  }
}

#undef G8_LDA
#undef G8_LDB
#undef G8_MFMA

// ---------------------------------------------------------------------------
// Flash attention v5 (round-7: setprio + defer-max).  Grid 512 blocks
// (XCD head-clustered), 4 waves, 32 q-rows/wave, kv-tile 64,
// DOUBLE-BUFFERED K/V (80 KB LDS, 2 blocks/CU).
// ---------------------------------------------------------------------------
__global__ __launch_bounds__(256, 2) void flash_attn(const u16* __restrict__ Q,
                                                     const u16* __restrict__ KV,
                                                     const u16* __restrict__ VT,
                                                     u16* __restrict__ O) {
  __shared__ u16 Ks[2][64 * 128];    // [kv][16 chunks], chunk^= (kv&15)
  __shared__ u16 Vs[2][128 * 64];    // [d][8 chunks],   chunk^= (d&7)
  __shared__ u16 Ps[4][32 * 64];     // per-wave [q][8 chunks], chunk^=((q&7)^(q>>3))
  const int tid = threadIdx.x;
  const int wave = tid >> 6, lane = tid & 63, l16 = lane & 15, quad = lane >> 4;
  const int d = blockIdx.x;
  const int bh = (d & 7) * 4 + ((d >> 3) & 3);
  const int qt = d >> 5;
  const int b = bh >> 4, h = bh & 15;
  const u16* Qb = Q + (size_t)b * 2048 * 2048 + h * 128;
  const u16* Kb = KV + (size_t)b * 2048 * 4096 + h * 128;
  const u16* Vb = VT + (size_t)bh * 128 * 2048;
  u16* Ob = O + (size_t)b * 2048 * 2048 + h * 128;
  const int q0 = qt * 128 + wave * 32;

  short8 qf[2][4];
#pragma unroll
  for (int t = 0; t < 2; ++t)
#pragma unroll
    for (int kd = 0; kd < 4; ++kd)
      qf[t][kd] = *(const short8*)&Qb[(size_t)(q0 + t * 16 + l16) * 2048 + kd * 32 + quad * 8];

  short8 onesf;
  {
    union { short8 s; u32 w[4]; } uo;
    const u32 o = (l16 == 0) ? 0x3F803F80u : 0u;
#pragma unroll
    for (int i = 0; i < 4; ++i) uo.w[i] = o;
    onesf = uo.s;
  }

  const floatx4 fz = {0.f, 0.f, 0.f, 0.f};
  floatx4 oacc[2][9];
  float m[2][4];
#pragma unroll
  for (int t = 0; t < 2; ++t) {
#pragma unroll
    for (int jd = 0; jd < 9; ++jd) oacc[t][jd] = fz;
#pragma unroll
    for (int r = 0; r < 4; ++r) m[t][r] = -1e30f;
  }

  u16* Psw = Ps[wave];
  const float sc2 = 0.12751775f;   // (1/sqrt(128)) * log2(e)
  const float THR2 = 11.5416f;     // defer-max threshold 8 (ln) in log2 space

  auto stage = [&](int buf, int kv0) {
#pragma unroll
    for (int c = 0; c < 4; ++c) {
      const int li = c * 256 + tid;
      const int krow = li >> 4, kdb = (li & 15) ^ (krow & 15);
      gld16(&Ks[buf][li * 8], Kb + (size_t)(kv0 + krow) * 4096 + kdb * 8);
      const int vrow = li >> 3, vdb = (li & 7) ^ (vrow & 7);
      gld16(&Vs[buf][li * 8], Vb + (size_t)vrow * 2048 + kv0 + vdb * 8);
    }
  };

  stage(0, 0);
  int cur = 0;

  for (int kt = 0; kt < 32; ++kt) {
    __syncthreads();
    if (kt < 31) stage(cur ^ 1, (kt + 1) * 64);
    const u16* Kc = Ks[cur];
    const u16* Vc = Vs[cur];

    floatx4 sacc[2][4];
#pragma unroll
    for (int t = 0; t < 2; ++t)
#pragma unroll
      for (int jn = 0; jn < 4; ++jn) sacc[t][jn] = fz;
    __builtin_amdgcn_s_setprio(1);
#pragma unroll
    for (int jn = 0; jn < 4; ++jn)
#pragma unroll
      for (int kd = 0; kd < 4; ++kd) {
        short8 kb = *(const short8*)&Kc[(jn * 16 + l16) * 128 + ((4 * kd + quad) ^ l16) * 8];
        sacc[0][jn] = __builtin_amdgcn_mfma_f32_16x16x32_bf16(qf[0][kd], kb, sacc[0][jn], 0, 0, 0);
        sacc[1][jn] = __builtin_amdgcn_mfma_f32_16x16x32_bf16(qf[1][kd], kb, sacc[1][jn], 0, 0, 0);
      }
    __builtin_amdgcn_s_setprio(0);

#pragma unroll
    for (int t = 0; t < 2; ++t) {
#pragma unroll
      for (int r = 0; r < 4; ++r) {
        float mx = fmaxf(fmaxf(sacc[t][0][r], sacc[t][1][r]),
                         fmaxf(sacc[t][2][r], sacc[t][3][r]));
#pragma unroll
        for (int off = 8; off > 0; off >>= 1) mx = fmaxf(mx, __shfl_xor(mx, off, 16));
        const float mxs = sc2 * mx;
        if (!__all(mxs - m[t][r] <= THR2)) {
          const float mnew = fmaxf(m[t][r], mxs);
          const float alpha = __builtin_amdgcn_exp2f(m[t][r] - mnew);
          m[t][r] = mnew;
#pragma unroll
          for (int jd = 0; jd < 9; ++jd) oacc[t][jd][r] *= alpha;
        }
        const float mrow = m[t][r];
        const int q = t * 16 + quad * 4 + r;               // 0..31
        const int mask = (q & 7) ^ (q >> 3);
        u16* prow = &Psw[q * 64 + (l16 & 7)];
#pragma unroll
        for (int jn = 0; jn < 4; ++jn) {
          const float p = __builtin_amdgcn_exp2f(fmaf(sc2, sacc[t][jn][r], -mrow));
          const int slot = (2 * jn + (l16 >> 3)) ^ mask;
          prow[slot * 8] = f2bf(p);
        }
      }
    }

    const int pmask0 = (l16 & 7) ^ (l16 >> 3);        // t=0
    const int pmask1 = (l16 & 7) ^ (2 + (l16 >> 3));  // t=1
    __builtin_amdgcn_s_setprio(1);
#pragma unroll
    for (int kk = 0; kk < 2; ++kk) {
      const int chunk = 4 * kk + quad;
      short8 pf0 = *(const short8*)&Psw[(l16) * 64 + (chunk ^ pmask0) * 8];
      short8 pf1 = *(const short8*)&Psw[(16 + l16) * 64 + (chunk ^ pmask1) * 8];
#pragma unroll
      for (int jd = 0; jd < 8; ++jd) {
        short8 vb = *(const short8*)&Vc[(jd * 16 + l16) * 64 + (chunk ^ (l16 & 7)) * 8];
        oacc[0][jd] = __builtin_amdgcn_mfma_f32_16x16x32_bf16(pf0, vb, oacc[0][jd], 0, 0, 0);
        oacc[1][jd] = __builtin_amdgcn_mfma_f32_16x16x32_bf16(pf1, vb, oacc[1][jd], 0, 0, 0);
      }
      oacc[0][8] = __builtin_amdgcn_mfma_f32_16x16x32_bf16(pf0, onesf, oacc[0][8], 0, 0, 0);
      oacc[1][8] = __builtin_amdgcn_mfma_f32_16x16x32_bf16(pf1, onesf, oacc[1][8], 0, 0, 0);
    }
    __builtin_amdgcn_s_setprio(0);
    cur ^= 1;
  }

#pragma unroll
  for (int t = 0; t < 2; ++t)
#pragma unroll
    for (int r = 0; r < 4; ++r) {
      const float l = __shfl(oacc[t][8][r], lane & 48);
      const float inv = 1.f / l;
      const size_t row = q0 + t * 16 + quad * 4 + r;
#pragma unroll
      for (int jd = 0; jd < 8; ++jd)
        Ob[row * 2048 + jd * 16 + l16] = f2bf(oacc[t][jd][r] * inv);
    }
}

// ---------------------------------------------------------------------------
extern "C" void kernel_launch(void* const* d_in, const int* in_sizes, int n_in,
                              void* d_out, int out_size, void* d_ws, size_t ws_size,
                              hipStream_t stream) {
  const float* x       = (const float*)d_in[0];
  const float* latents = (const float*)d_in[1];
  const float* w_q     = (const float*)d_in[2];
  const float* w_kv    = (const float*)d_in[3];
  const float* w_out   = (const float*)d_in[4];
  const float* ln1_g   = (const float*)d_in[5];
  const float* ln1_b   = (const float*)d_in[6];
  const float* ln2_g   = (const float*)d_in[7];
  const float* ln2_b   = (const float*)d_in[8];

  char* ws = (char*)d_ws;
  u16* xn    = (u16*)(ws);              // LN(x)        [dead after kv gemm]
  u16* lnl   = (u16*)(ws + 16777216);   // LN(latents)  [dead after q gemm]
  u16* wqT   = (u16*)(ws + 41943040);
  u16* wkvT  = (u16*)(ws + 54525952);
  u16* woutT = (u16*)(ws + 71303168);
  u16* qb    = (u16*)(ws + 83886080);
  u16* kvb   = (u16*)(ws + 100663296);
  u16* vTb   = lnl;                     // alias (q gemm consumed lnl already)
  u16* attn  = xn;                      // alias

  ln_cast<2048><<<dim3(4096), 256, 0, stream>>>(x, ln1_g, ln1_b, xn);
  ln_cast<3072><<<dim3(4096), 256, 0, stream>>>(latents, ln2_g, ln2_b, lnl);

  transpose_cast<<<dim3(64, 96), dim3(32, 8), 0, stream>>>(w_q, wqT, 3072, 2048);
  transpose_cast<<<dim3(128, 64), dim3(32, 8), 0, stream>>>(w_kv, wkvT, 2048, 4096);
  transpose_cast<<<dim3(96, 64), dim3(32, 8), 0, stream>>>(w_out, woutT, 2048, 3072);

  gemm_bt<u16><<<dim3(16, 32), 256, 0, stream>>>(lnl, wqT, qb, 4096, 2048, 3072);
  // kv GEMM: K half -> kvb, V half -> vTb transposed (fused transpose_v)
  gemm_bt8<u16><<<dim3(16, 16), 512, 0, stream>>>(xn, wkvT, kvb, 4096, 4096, 2048,
                                                  vTb, 2048);

  flash_attn<<<dim3(512), 256, 0, stream>>>(qb, kvb, vTb, attn);

  gemm_bt8<float><<<dim3(12, 16), 512, 0, stream>>>(attn, woutT, (float*)d_out,
                                                    4096, 3072, 2048, nullptr,
                                                    1 << 30);
}

// Round 6
// 494.030 us; speedup vs baseline: 1.0631x; 1.0243x over previous
//
#include <hip/hip_runtime.h>
#include <type_traits>

// PerceiverAttentionCA on MI355X (gfx950).  Round 10:
//  - NEW gemm_bt4: 256x128-tile 4-phase GEMM for the q GEMM (grid 16x16 =
//    256 wgs, full machine; 256^2 would give only 128).  Same discipline as
//    gemm_bt8: counted vmcnt (never 0 mid-loop), raw s_barrier, setprio
//    around MFMA, XCD swizzle.  B-frags read once per K-tile, reused in
//    registers across both phases.  LDS 96 KB (A dbuf 64K + B dbuf 32K).
//    Ledger (half-tile = 2 gld16/thread): prologue {A0,B,A1; vmcnt(2)};
//    p0: +{A0',B'} -> 6 outst, MFMA mh=0, vmcnt(4) => A1(t) landed;
//    p1: +{A1'} -> 6 outst, MFMA mh=1, vmcnt(2) => A0',B' landed.
//  - Kernel merges: ln_cast2 (x + latents in one dispatch), transpose_cast3
//    (all 3 weight transposes in one dispatch).  11 -> 8 dispatches.
//  - flash_attn, gemm_bt8 (kv + out GEMMs, V^T fused epilogue): unchanged.

using u16 = unsigned short;
using u32 = unsigned int;
typedef __attribute__((ext_vector_type(8))) short short8;   // 8 x bf16 bits
typedef __attribute__((ext_vector_type(4))) float floatx4;  // MFMA accumulator
typedef __attribute__((ext_vector_type(4))) unsigned short u16x4;

typedef __attribute__((address_space(1))) const unsigned int gu32;
typedef __attribute__((address_space(3))) unsigned int lu32;

__device__ __forceinline__ void gld16(void* lds, const void* g) {
  __builtin_amdgcn_global_load_lds((gu32*)g, (lu32*)lds, 16, 0, 0);
}

__device__ inline u16 f2bf(float f) {
  u32 u = __float_as_uint(f);
  u32 r = (u + 0x7FFFu + ((u >> 16) & 1u)) >> 16;   // RNE
  return (u16)r;
}

// ---------------------------------------------------------------------------
// LayerNorm + cast to bf16 (merged x + latents).  One block per row.
// ---------------------------------------------------------------------------
template <int L>
__device__ __forceinline__ void ln_body(const float* __restrict__ in,
                                        const float* __restrict__ gw,
                                        const float* __restrict__ bw,
                                        u16* __restrict__ out, int row) {
  constexpr int C4 = L / 1024;
  const int t = threadIdx.x;
  const float* rp = in + (size_t)row * L;
  float4 v[C4];
  float s = 0.f, ss = 0.f;
#pragma unroll
  for (int c = 0; c < C4; ++c) {
    v[c] = *(const float4*)(rp + (c * 256 + t) * 4);
    s += v[c].x + v[c].y + v[c].z + v[c].w;
    ss += v[c].x * v[c].x + v[c].y * v[c].y + v[c].z * v[c].z + v[c].w * v[c].w;
  }
#pragma unroll
  for (int off = 32; off > 0; off >>= 1) {
    s += __shfl_down(s, off);
    ss += __shfl_down(ss, off);
  }
  __shared__ float red[8];
  const int wave = t >> 6, lane = t & 63;
  if (lane == 0) { red[wave] = s; red[4 + wave] = ss; }
  __syncthreads();
  const float tot = red[0] + red[1] + red[2] + red[3];
  const float tss = red[4] + red[5] + red[6] + red[7];
  const float mu = tot * (1.f / L);
  const float rstd = rsqrtf(tss * (1.f / L) - mu * mu + 1e-5f);
  u16* op = out + (size_t)row * L;
#pragma unroll
  for (int c = 0; c < C4; ++c) {
    const int base = (c * 256 + t) * 4;
    float4 gv = *(const float4*)(gw + base);
    float4 bv = *(const float4*)(bw + base);
    u32 p0 = (u32)f2bf((v[c].x - mu) * rstd * gv.x + bv.x) |
             ((u32)f2bf((v[c].y - mu) * rstd * gv.y + bv.y) << 16);
    u32 p1 = (u32)f2bf((v[c].z - mu) * rstd * gv.z + bv.z) |
             ((u32)f2bf((v[c].w - mu) * rstd * gv.w + bv.w) << 16);
    uint2 pk; pk.x = p0; pk.y = p1;
    *(uint2*)(op + base) = pk;
  }
}

__global__ __launch_bounds__(256) void ln_cast2(const float* __restrict__ x,
                                                const float* __restrict__ lat,
                                                const float* __restrict__ g1,
                                                const float* __restrict__ b1,
                                                const float* __restrict__ g2,
                                                const float* __restrict__ b2,
                                                u16* __restrict__ xn,
                                                u16* __restrict__ lnl) {
  const int bid = blockIdx.x;
  if (bid < 4096) ln_body<2048>(x, g1, b1, xn, bid);
  else            ln_body<3072>(lat, g2, b2, lnl, bid - 4096);
}

// ---------------------------------------------------------------------------
// Transpose + cast, all three weights in one dispatch.  Block (32,8).
// wq: 3072x2048 -> 64x96 tiles; wkv: 2048x4096 -> 128x64; wout: 2048x3072.
// ---------------------------------------------------------------------------
__global__ __launch_bounds__(256) void transpose_cast3(const float* __restrict__ wq,
                                                       const float* __restrict__ wkv,
                                                       const float* __restrict__ wout,
                                                       u16* __restrict__ oq,
                                                       u16* __restrict__ okv,
                                                       u16* __restrict__ oout) {
  __shared__ u16 tile[32][33];
  const int bid = blockIdx.x;
  const float* in; u16* out; int R, C, gx, tb;
  if (bid < 6144)       { in = wq;   out = oq;   R = 3072; C = 2048; gx = 64;  tb = bid; }
  else if (bid < 14336) { in = wkv;  out = okv;  R = 2048; C = 4096; gx = 128; tb = bid - 6144; }
  else                  { in = wout; out = oout; R = 2048; C = 3072; gx = 96;  tb = bid - 14336; }
  const int c0 = (tb % gx) * 32, r0 = (tb / gx) * 32;
  const int x = threadIdx.x, y = threadIdx.y;
#pragma unroll
  for (int j = 0; j < 4; ++j)
    tile[y + 8 * j][x] = f2bf(in[(size_t)(r0 + y + 8 * j) * C + c0 + x]);
  __syncthreads();
#pragma unroll
  for (int j = 0; j < 4; ++j)
    out[(size_t)(c0 + y + 8 * j) * R + r0 + x] = tile[x][y + 8 * j];
}

// ---------------------------------------------------------------------------
// shared barrier / wait macros for the phase-structured GEMMs
// ---------------------------------------------------------------------------
#define GBAR()                                         \
  do {                                                 \
    asm volatile("" ::: "memory");                     \
    __builtin_amdgcn_s_barrier();                      \
    asm volatile("" ::: "memory");                     \
  } while (0)
#define VMW(N) asm volatile("s_waitcnt vmcnt(" #N ")" ::: "memory")

// ---------------------------------------------------------------------------
// 4-phase 256x128 GEMM  C(MxN) = A(MxK) * Bt(NxK)^T.  512 thr / 8 waves.
// Grid (N/128, M/256).  u16 output only (q GEMM).  See header for ledger.
// ---------------------------------------------------------------------------
__global__ __launch_bounds__(512, 2) void gemm_bt4(const u16* __restrict__ A,
                                                   const u16* __restrict__ Bt,
                                                   u16* __restrict__ C,
                                                   int M, int N, int K) {
  __shared__ u16 As[2][2][8192];   // [buf][half][128][64]  64 KB
  __shared__ u16 Bs[2][8192];      // [buf][128][64]        32 KB
  (void)M;
  const int tid = threadIdx.x;
  const int wave = tid >> 6, lane = tid & 63, l16 = lane & 15, quad = lane >> 4;
  const int wr = wave >> 1;      // 0..3: 32-row strip in the 128-row half
  const int wc = wave & 1;       // 0..1: 64-col strip in the 128-col tile
  const int nwg = gridDim.x * gridDim.y;
  const int bid0 = blockIdx.y * gridDim.x + blockIdx.x;
  const int bid = (bid0 & 7) * (nwg >> 3) + (bid0 >> 3);
  const int bx = bid % gridDim.x, by = bid / gridDim.x;
  const long m0 = (long)by * 256, n0 = (long)bx * 128;

  const int srow = tid >> 3;                       // 0..63
  const int gc = ((tid & 7) ^ (srow & 7)) * 8;     // u16 offset

  auto stageAh = [&](int bufn, int mh, int k0) {
#pragma unroll
    for (int c = 0; c < 2; ++c)
      gld16(&As[bufn][mh][(c * 512 + tid) * 8],
            A + (size_t)(m0 + mh * 128 + c * 64 + srow) * K + k0 + gc);
  };
  auto stageBh = [&](int bufn, int k0) {
#pragma unroll
    for (int c = 0; c < 2; ++c)
      gld16(&Bs[bufn][(c * 512 + tid) * 8],
            Bt + (size_t)(n0 + c * 64 + srow) * K + k0 + gc);
  };

  const floatx4 fz = {0.f, 0.f, 0.f, 0.f};
  floatx4 acc[2][2][4];
#pragma unroll
  for (int a = 0; a < 2; ++a)
#pragma unroll
    for (int b = 0; b < 2; ++b)
#pragma unroll
      for (int c = 0; c < 4; ++c) acc[a][b][c] = fz;

  short8 af[2][2], bf[4][2];
  const int swz = l16 & 7;

  // prologue: A0(0), B(0), A1(0); wait A0,B (leave A1 in flight)
  stageAh(0, 0, 0);
  stageBh(0, 0);
  stageAh(0, 1, 0);
  VMW(2);
  GBAR();

  const int NT = K >> 6;
  for (int t = 0; t < NT; ++t) {
    const int buf = t & 1;
    const int kn = (t + 1) << 6;
    const bool pre = (t + 1 < NT);

    // ---- phase 0: half mh=0 (B-frags loaded here, reused in phase 1) ----
    {
      const u16* Ab_ = &As[buf][0][(wr * 32 + l16) * 64];
#pragma unroll
      for (int mi = 0; mi < 2; ++mi)
#pragma unroll
        for (int ks = 0; ks < 2; ++ks)
          af[mi][ks] = *(const short8*)&Ab_[mi * 1024 + ((4 * ks + quad) ^ swz) * 8];
      const u16* Bb_ = &Bs[buf][(wc * 64 + l16) * 64];
#pragma unroll
      for (int ni = 0; ni < 4; ++ni)
#pragma unroll
        for (int ks = 0; ks < 2; ++ks)
          bf[ni][ks] = *(const short8*)&Bb_[ni * 1024 + ((4 * ks + quad) ^ swz) * 8];
    }
    if (pre) { stageAh(buf ^ 1, 0, kn); stageBh(buf ^ 1, kn); }
    GBAR();
    __builtin_amdgcn_s_setprio(1);
#pragma unroll
    for (int ks = 0; ks < 2; ++ks)
#pragma unroll
      for (int mi = 0; mi < 2; ++mi)
#pragma unroll
        for (int ni = 0; ni < 4; ++ni)
          acc[0][mi][ni] = __builtin_amdgcn_mfma_f32_16x16x32_bf16(
              af[mi][ks], bf[ni][ks], acc[0][mi][ni], 0, 0, 0);
    __builtin_amdgcn_s_setprio(0);
    if (pre) { VMW(4); } else { VMW(0); }   // A1(t) landed
    GBAR();

    // ---- phase 1: half mh=1 ----
    {
      const u16* Ab_ = &As[buf][1][(wr * 32 + l16) * 64];
#pragma unroll
      for (int mi = 0; mi < 2; ++mi)
#pragma unroll
        for (int ks = 0; ks < 2; ++ks)
          af[mi][ks] = *(const short8*)&Ab_[mi * 1024 + ((4 * ks + quad) ^ swz) * 8];
    }
    if (pre) stageAh(buf ^ 1, 1, kn);
    GBAR();
    __builtin_amdgcn_s_setprio(1);
#pragma unroll
    for (int ks = 0; ks < 2; ++ks)
#pragma unroll
      for (int mi = 0; mi < 2; ++mi)
#pragma unroll
        for (int ni = 0; ni < 4; ++ni)
          acc[1][mi][ni] = __builtin_amdgcn_mfma_f32_16x16x32_bf16(
              af[mi][ks], bf[ni][ks], acc[1][mi][ni], 0, 0, 0);
    __builtin_amdgcn_s_setprio(0);
    if (pre) { VMW(2); }                    // A0',B' landed
    GBAR();
  }

  // epilogue
#pragma unroll
  for (int mh = 0; mh < 2; ++mh)
#pragma unroll
    for (int mi = 0; mi < 2; ++mi)
#pragma unroll
      for (int rr = 0; rr < 4; ++rr) {
        const long row = m0 + mh * 128 + wr * 32 + mi * 16 + quad * 4 + rr;
#pragma unroll
        for (int ni = 0; ni < 4; ++ni) {
          const long col = n0 + wc * 64 + ni * 16 + l16;
          C[row * N + col] = f2bf(acc[mh][mi][ni][rr]);
        }
      }
}

// ---------------------------------------------------------------------------
// 8-phase 256x256 GEMM  C(MxN) = A(MxK) * Bt(NxK)^T.   512 thr, 8 waves.
// vmcnt ledger (round-7): in-flight never below 2 half-tiles; vmcnt(4)
// closes phases 0/1/3.  V^T epilogue (round-9): blocks with n0 >= vcol0
// write acc as vT (b,h,128,2048) via LDS-staged transpose, coalesced.
// ---------------------------------------------------------------------------
#define G8_LDA(MH)                                                             \
  {                                                                            \
    const u16* Ab_ = &As[buf][(MH) * 8192 + (wr * 32 + l16) * 64];             \
    _Pragma("unroll") for (int mi = 0; mi < 2; ++mi)                           \
    _Pragma("unroll") for (int ks = 0; ks < 2; ++ks)                           \
      af[mi][ks] = *(const short8*)&Ab_[mi * 1024 + ((4 * ks + quad) ^ swz) * 8]; \
  }
#define G8_LDB(DST, NH)                                                        \
  {                                                                            \
    const u16* Bb_ = &Bs[buf][(NH) * 8192 + (wc * 64 + l16) * 64];             \
    _Pragma("unroll") for (int ni = 0; ni < 4; ++ni)                           \
    _Pragma("unroll") for (int ks = 0; ks < 2; ++ks)                           \
      DST[ni][ks] = *(const short8*)&Bb_[ni * 1024 + ((4 * ks + quad) ^ swz) * 8]; \
  }
#define G8_MFMA(MH, BFX, NH)                                                   \
  __builtin_amdgcn_s_setprio(1);                                               \
  _Pragma("unroll") for (int ks = 0; ks < 2; ++ks)                             \
  _Pragma("unroll") for (int mi = 0; mi < 2; ++mi)                             \
  _Pragma("unroll") for (int ni = 0; ni < 4; ++ni)                             \
    acc[MH][mi][NH][ni] = __builtin_amdgcn_mfma_f32_16x16x32_bf16(             \
        af[mi][ks], BFX[ni][ks], acc[MH][mi][NH][ni], 0, 0, 0);                \
  __builtin_amdgcn_s_setprio(0);

template <typename OutT>
__global__ __launch_bounds__(512, 2) void gemm_bt8(const u16* __restrict__ A,
                                                   const u16* __restrict__ Bt,
                                                   OutT* __restrict__ C,
                                                   int M, int N, int K,
                                                   u16* __restrict__ vT,
                                                   int vcol0) {
  __shared__ u16 As[2][16384];   // [buf][half][128][64]
  __shared__ u16 Bs[2][16384];
  (void)M;
  const int tid = threadIdx.x;
  const int wave = tid >> 6, lane = tid & 63, l16 = lane & 15, quad = lane >> 4;
  const int wr = wave >> 1;      // 0..3: 32-row strip within the 128-row half
  const int wc = wave & 1;       // 0..1: 64-col strip within the 128-col half
  const int nwg = gridDim.x * gridDim.y;
  const int bid0 = blockIdx.y * gridDim.x + blockIdx.x;
  const int bid = (bid0 & 7) * (nwg >> 3) + (bid0 >> 3);
  const int bx = bid % gridDim.x, by = bid / gridDim.x;
  const long m0 = (long)by * 256, n0 = (long)bx * 256;

  const int srow = tid >> 3;                       // 0..63
  const int gc = ((tid & 7) ^ (srow & 7)) * 8;     // u16 offset

  auto stageA = [&](int bufn, int h, int k0) {
#pragma unroll
    for (int c = 0; c < 2; ++c)
      gld16(&As[bufn][h * 8192 + (c * 512 + tid) * 8],
            A + (size_t)(m0 + h * 128 + c * 64 + srow) * K + k0 + gc);
  };
  auto stageB = [&](int bufn, int h, int k0) {
#pragma unroll
    for (int c = 0; c < 2; ++c)
      gld16(&Bs[bufn][h * 8192 + (c * 512 + tid) * 8],
            Bt + (size_t)(n0 + h * 128 + c * 64 + srow) * K + k0 + gc);
  };

  const floatx4 fz = {0.f, 0.f, 0.f, 0.f};
  floatx4 acc[2][2][2][4];
#pragma unroll
  for (int a = 0; a < 2; ++a)
#pragma unroll
    for (int b = 0; b < 2; ++b)
#pragma unroll
      for (int c = 0; c < 2; ++c)
#pragma unroll
        for (int d = 0; d < 4; ++d) acc[a][b][c][d] = fz;

  short8 af[2][2], bf0[4][2], bf1[4][2];
  const int swz = l16 & 7;

  // prologue: stage tile 0 in need order; wait A0,B0 (leave B1,A1 in flight)
  stageA(0, 0, 0);
  stageB(0, 0, 0);
  stageB(0, 1, 0);
  stageA(0, 1, 0);
  VMW(4);
  GBAR();

  const int NT = K >> 6;
  for (int t = 0; t < NT; ++t) {
    const int buf = t & 1;
    const int kn = (t + 1) << 6;
    const bool pre = (t + 1 < NT);

    // ---- phase 0: quadrant (0,0) ----
    G8_LDA(0);
    G8_LDB(bf0, 0);
    if (pre) stageA(buf ^ 1, 0, kn);
    GBAR();
    G8_MFMA(0, bf0, 0);
    if (pre) { VMW(4); } else { VMW(2); }   // B1(t) landed
    GBAR();

    // ---- phase 1: quadrant (0,1) ----
    G8_LDB(bf1, 1);
    if (pre) stageB(buf ^ 1, 0, kn);
    GBAR();
    G8_MFMA(0, bf1, 1);
    if (pre) { VMW(4); } else { VMW(0); }   // A1(t) landed
    GBAR();

    // ---- phase 2: quadrant (1,0) ----
    G8_LDA(1);
    if (pre) stageB(buf ^ 1, 1, kn);
    GBAR();
    G8_MFMA(1, bf0, 0);
    GBAR();

    // ---- phase 3: quadrant (1,1) ----
    if (pre) stageA(buf ^ 1, 1, kn);
    GBAR();
    G8_MFMA(1, bf1, 1);
    if (pre) { VMW(4); }                    // A0,B0(t+1) landed
    GBAR();
  }

  // epilogue
  bool vpath = false;
  if constexpr (std::is_same<OutT, u16>::value) vpath = (n0 >= vcol0);
  if (vpath) {
    // Fused transpose_v, coalesced via padded LDS tile [128][136] u16.
    u16* tl = (u16*)&As[0][0];          // 128*136*2 = 34816 B scratch
#pragma unroll
    for (int mh = 0; mh < 2; ++mh)
#pragma unroll
      for (int nh = 0; nh < 2; ++nh) {
        const long R0 = m0 + mh * 128;
        const long bb = R0 >> 11, nn0 = R0 & 2047;
        const long hh = (n0 + nh * 128 - vcol0) >> 7;
        __syncthreads();                // prev quadrant's LDS reads complete
        const int dl0 = wc * 64 + l16;
        const int nl0 = wr * 32 + quad * 4;
#pragma unroll
        for (int mi = 0; mi < 2; ++mi)
#pragma unroll
          for (int ni = 0; ni < 4; ++ni) {
            u16x4 pk;
#pragma unroll
            for (int rr = 0; rr < 4; ++rr) pk[rr] = f2bf(acc[mh][mi][nh][ni][rr]);
            *(u16x4*)&tl[(dl0 + ni * 16) * 136 + nl0 + mi * 16] = pk;
          }
        __syncthreads();
        const int d = tid >> 2, sg = (tid & 3) * 32;
        u16* gp = &vT[(((bb * 16 + hh) * 128 + d) << 11) + nn0 + sg];
        const u16* lp = &tl[d * 136 + sg];
#pragma unroll
        for (int j = 0; j < 4; ++j)
          *(short8*)&gp[j * 8] = *(const short8*)&lp[j * 8];
      }
  } else {
#pragma unroll
    for (int mh = 0; mh < 2; ++mh)
#pragma unroll
      for (int mi = 0; mi < 2; ++mi)
#pragma unroll
        for (int rr = 0; rr < 4; ++rr) {
          const long row = m0 + mh * 128 + wr * 32 + mi * 16 + quad * 4 + rr;
#pragma unroll
          for (int nh = 0; nh < 2; ++nh)
#pragma unroll
            for (int ni = 0; ni < 4; ++ni) {
              const long col = n0 + nh * 128 + wc * 64 + ni * 16 + l16;
              if constexpr (std::is_same<OutT, float>::value)
                C[row * N + col] = acc[mh][mi][nh][ni][rr];
              else
                C[row * N + col] = f2bf(acc[mh][mi][nh][ni][rr]);
            }
        }
  }
}

#undef G8_LDA
#undef G8_LDB
#undef G8_MFMA

// ---------------------------------------------------------------------------
// Flash attention v5 (round-7: setprio + defer-max).  Grid 512 blocks
// (XCD head-clustered), 4 waves, 32 q-rows/wave, kv-tile 64,
// DOUBLE-BUFFERED K/V (80 KB LDS, 2 blocks/CU).
// ---------------------------------------------------------------------------
__global__ __launch_bounds__(256, 2) void flash_attn(const u16* __restrict__ Q,
                                                     const u16* __restrict__ KV,
                                                     const u16* __restrict__ VT,
                                                     u16* __restrict__ O) {
  __shared__ u16 Ks[2][64 * 128];    // [kv][16 chunks], chunk^= (kv&15)
  __shared__ u16 Vs[2][128 * 64];    // [d][8 chunks],   chunk^= (d&7)
  __shared__ u16 Ps[4][32 * 64];     // per-wave [q][8 chunks], chunk^=((q&7)^(q>>3))
  const int tid = threadIdx.x;
  const int wave = tid >> 6, lane = tid & 63, l16 = lane & 15, quad = lane >> 4;
  const int d = blockIdx.x;
  const int bh = (d & 7) * 4 + ((d >> 3) & 3);
  const int qt = d >> 5;
  const int b = bh >> 4, h = bh & 15;
  const u16* Qb = Q + (size_t)b * 2048 * 2048 + h * 128;
  const u16* Kb = KV + (size_t)b * 2048 * 4096 + h * 128;
  const u16* Vb = VT + (size_t)bh * 128 * 2048;
  u16* Ob = O + (size_t)b * 2048 * 2048 + h * 128;
  const int q0 = qt * 128 + wave * 32;

  short8 qf[2][4];
#pragma unroll
  for (int t = 0; t < 2; ++t)
#pragma unroll
    for (int kd = 0; kd < 4; ++kd)
      qf[t][kd] = *(const short8*)&Qb[(size_t)(q0 + t * 16 + l16) * 2048 + kd * 32 + quad * 8];

  short8 onesf;
  {
    union { short8 s; u32 w[4]; } uo;
    const u32 o = (l16 == 0) ? 0x3F803F80u : 0u;
#pragma unroll
    for (int i = 0; i < 4; ++i) uo.w[i] = o;
    onesf = uo.s;
  }

  const floatx4 fz = {0.f, 0.f, 0.f, 0.f};
  floatx4 oacc[2][9];
  float m[2][4];
#pragma unroll
  for (int t = 0; t < 2; ++t) {
#pragma unroll
    for (int jd = 0; jd < 9; ++jd) oacc[t][jd] = fz;
#pragma unroll
    for (int r = 0; r < 4; ++r) m[t][r] = -1e30f;
  }

  u16* Psw = Ps[wave];
  const float sc2 = 0.12751775f;   // (1/sqrt(128)) * log2(e)
  const float THR2 = 11.5416f;     // defer-max threshold 8 (ln) in log2 space

  auto stage = [&](int buf, int kv0) {
#pragma unroll
    for (int c = 0; c < 4; ++c) {
      const int li = c * 256 + tid;
      const int krow = li >> 4, kdb = (li & 15) ^ (krow & 15);
      gld16(&Ks[buf][li * 8], Kb + (size_t)(kv0 + krow) * 4096 + kdb * 8);
      const int vrow = li >> 3, vdb = (li & 7) ^ (vrow & 7);
      gld16(&Vs[buf][li * 8], Vb + (size_t)vrow * 2048 + kv0 + vdb * 8);
    }
  };

  stage(0, 0);
  int cur = 0;

  for (int kt = 0; kt < 32; ++kt) {
    __syncthreads();
    if (kt < 31) stage(cur ^ 1, (kt + 1) * 64);
    const u16* Kc = Ks[cur];
    const u16* Vc = Vs[cur];

    floatx4 sacc[2][4];
#pragma unroll
    for (int t = 0; t < 2; ++t)
#pragma unroll
      for (int jn = 0; jn < 4; ++jn) sacc[t][jn] = fz;
    __builtin_amdgcn_s_setprio(1);
#pragma unroll
    for (int jn = 0; jn < 4; ++jn)
#pragma unroll
      for (int kd = 0; kd < 4; ++kd) {
        short8 kb = *(const short8*)&Kc[(jn * 16 + l16) * 128 + ((4 * kd + quad) ^ l16) * 8];
        sacc[0][jn] = __builtin_amdgcn_mfma_f32_16x16x32_bf16(qf[0][kd], kb, sacc[0][jn], 0, 0, 0);
        sacc[1][jn] = __builtin_amdgcn_mfma_f32_16x16x32_bf16(qf[1][kd], kb, sacc[1][jn], 0, 0, 0);
      }
    __builtin_amdgcn_s_setprio(0);

#pragma unroll
    for (int t = 0; t < 2; ++t) {
#pragma unroll
      for (int r = 0; r < 4; ++r) {
        float mx = fmaxf(fmaxf(sacc[t][0][r], sacc[t][1][r]),
                         fmaxf(sacc[t][2][r], sacc[t][3][r]));
#pragma unroll
        for (int off = 8; off > 0; off >>= 1) mx = fmaxf(mx, __shfl_xor(mx, off, 16));
        const float mxs = sc2 * mx;
        if (!__all(mxs - m[t][r] <= THR2)) {
          const float mnew = fmaxf(m[t][r], mxs);
          const float alpha = __builtin_amdgcn_exp2f(m[t][r] - mnew);
          m[t][r] = mnew;
#pragma unroll
          for (int jd = 0; jd < 9; ++jd) oacc[t][jd][r] *= alpha;
        }
        const float mrow = m[t][r];
        const int q = t * 16 + quad * 4 + r;               // 0..31
        const int mask = (q & 7) ^ (q >> 3);
        u16* prow = &Psw[q * 64 + (l16 & 7)];
#pragma unroll
        for (int jn = 0; jn < 4; ++jn) {
          const float p = __builtin_amdgcn_exp2f(fmaf(sc2, sacc[t][jn][r], -mrow));
          const int slot = (2 * jn + (l16 >> 3)) ^ mask;
          prow[slot * 8] = f2bf(p);
        }
      }
    }

    const int pmask0 = (l16 & 7) ^ (l16 >> 3);        // t=0
    const int pmask1 = (l16 & 7) ^ (2 + (l16 >> 3));  // t=1
    __builtin_amdgcn_s_setprio(1);
#pragma unroll
    for (int kk = 0; kk < 2; ++kk) {
      const int chunk = 4 * kk + quad;
      short8 pf0 = *(const short8*)&Psw[(l16) * 64 + (chunk ^ pmask0) * 8];
      short8 pf1 = *(const short8*)&Psw[(16 + l16) * 64 + (chunk ^ pmask1) * 8];
#pragma unroll
      for (int jd = 0; jd < 8; ++jd) {
        short8 vb = *(const short8*)&Vc[(jd * 16 + l16) * 64 + (chunk ^ (l16 & 7)) * 8];
        oacc[0][jd] = __builtin_amdgcn_mfma_f32_16x16x32_bf16(pf0, vb, oacc[0][jd], 0, 0, 0);
        oacc[1][jd] = __builtin_amdgcn_mfma_f32_16x16x32_bf16(pf1, vb, oacc[1][jd], 0, 0, 0);
      }
      oacc[0][8] = __builtin_amdgcn_mfma_f32_16x16x32_bf16(pf0, onesf, oacc[0][8], 0, 0, 0);
      oacc[1][8] = __builtin_amdgcn_mfma_f32_16x16x32_bf16(pf1, onesf, oacc[1][8], 0, 0, 0);
    }
    __builtin_amdgcn_s_setprio(0);
    cur ^= 1;
  }

#pragma unroll
  for (int t = 0; t < 2; ++t)
#pragma unroll
    for (int r = 0; r < 4; ++r) {
      const float l = __shfl(oacc[t][8][r], lane & 48);
      const float inv = 1.f / l;
      const size_t row = q0 + t * 16 + quad * 4 + r;
#pragma unroll
      for (int jd = 0; jd < 8; ++jd)
        Ob[row * 2048 + jd * 16 + l16] = f2bf(oacc[t][jd][r] * inv);
    }
}

// ---------------------------------------------------------------------------
extern "C" void kernel_launch(void* const* d_in, const int* in_sizes, int n_in,
                              void* d_out, int out_size, void* d_ws, size_t ws_size,
                              hipStream_t stream) {
  const float* x       = (const float*)d_in[0];
  const float* latents = (const float*)d_in[1];
  const float* w_q     = (const float*)d_in[2];
  const float* w_kv    = (const float*)d_in[3];
  const float* w_out   = (const float*)d_in[4];
  const float* ln1_g   = (const float*)d_in[5];
  const float* ln1_b   = (const float*)d_in[6];
  const float* ln2_g   = (const float*)d_in[7];
  const float* ln2_b   = (const float*)d_in[8];

  char* ws = (char*)d_ws;
  u16* xn    = (u16*)(ws);              // LN(x)        [dead after kv gemm]
  u16* lnl   = (u16*)(ws + 16777216);   // LN(latents)  [dead after q gemm]
  u16* wqT   = (u16*)(ws + 41943040);
  u16* wkvT  = (u16*)(ws + 54525952);
  u16* woutT = (u16*)(ws + 71303168);
  u16* qb    = (u16*)(ws + 83886080);
  u16* kvb   = (u16*)(ws + 100663296);
  u16* vTb   = lnl;                     // alias (q gemm consumed lnl already)
  u16* attn  = xn;                      // alias

  ln_cast2<<<dim3(8192), 256, 0, stream>>>(x, latents, ln1_g, ln1_b,
                                           ln2_g, ln2_b, xn, lnl);

  transpose_cast3<<<dim3(20480), dim3(32, 8), 0, stream>>>(w_q, w_kv, w_out,
                                                           wqT, wkvT, woutT);

  gemm_bt4<<<dim3(16, 16), 512, 0, stream>>>(lnl, wqT, qb, 4096, 2048, 3072);
  // kv GEMM: K half -> kvb, V half -> vTb transposed (fused transpose_v)
  gemm_bt8<u16><<<dim3(16, 16), 512, 0, stream>>>(xn, wkvT, kvb, 4096, 4096, 2048,
                                                  vTb, 2048);

  flash_attn<<<dim3(512), 256, 0, stream>>>(qb, kvb, vTb, attn);

  gemm_bt8<float><<<dim3(12, 16), 512, 0, stream>>>(attn, woutT, (float*)d_out,
                                                    4096, 3072, 2048, nullptr,
                                                    1 << 30);
}